// Round 1
// baseline (369.123 us; speedup 1.0000x reference)
//
#include <hip/hip_runtime.h>

// Problem constants (from reference)
#define P_TOTAL 16384      // H*W pixels
#define KN      16         // kernels per pixel
#define CK      144        // in_channel * kernel_size
#define BATCH   8
#define IMG     262144     // C*H*W
#define PSTRIDE 12         // padded LDS row stride in floats (48B: float4-aligned, 2-way bank alias only)

__global__ __launch_bounds__(256) void abc2d_kernel(
    const float* __restrict__ x,      // [B*IMG] flattened
    const float* __restrict__ w,      // [P, KN, CK]
    const int*   __restrict__ hidx,   // [P, CK] (int32 from harness)
    float* __restrict__ out)          // [B, KN, P]
{
    __shared__ float patch[CK * PSTRIDE];   // patch[c][b], b in [0,8)

    // XCD swizzle: blocks are dispatched round-robin over 8 XCDs.
    // Map so consecutive p values run on the same XCD -> output lines
    // (p-contiguous) merge in one XCD's L2 instead of splintering.
    const int bid = blockIdx.x;
    const int p   = (bid & 7) * (P_TOTAL / 8) + (bid >> 3);

    const int t = threadIdx.x;

    // ---------- gather phase: 1152 divergent loads ----------
    const int* hp = hidx + p * CK;
    for (int j = t; j < CK * BATCH; j += 256) {
        const int c = j >> 3;      // 8 consecutive threads share one idx
        const int b = j & 7;
        const int id = hp[c];
        patch[c * PSTRIDE + b] = x[id + b * IMG];
    }
    __syncthreads();

    // ---------- compute phase ----------
    // thread t: k = t>>4 (0..15), cs = t&15 (c-slice)
    const int k  = t >> 4;
    const int cs = t & 15;
    const float* wp = w + (size_t)p * (KN * CK) + (size_t)k * CK;

    float acc[BATCH];
#pragma unroll
    for (int b = 0; b < BATCH; ++b) acc[b] = 0.f;

    // c covered in float4 chunks: c0 = i*64 + cs*4; i=0,1 full, i=2 only cs<4
#pragma unroll
    for (int i = 0; i < 3; ++i) {
        const int c0 = i * 64 + cs * 4;
        if (c0 < CK) {
            const float4 wv = *reinterpret_cast<const float4*>(wp + c0);
            const float wa[4] = {wv.x, wv.y, wv.z, wv.w};
#pragma unroll
            for (int j = 0; j < 4; ++j) {
                const int c = c0 + j;
                const float* pr = &patch[c * PSTRIDE];
                const float4 p0 = *reinterpret_cast<const float4*>(pr);
                const float4 p1 = *reinterpret_cast<const float4*>(pr + 4);
                acc[0] += wa[j] * p0.x;
                acc[1] += wa[j] * p0.y;
                acc[2] += wa[j] * p0.z;
                acc[3] += wa[j] * p0.w;
                acc[4] += wa[j] * p1.x;
                acc[5] += wa[j] * p1.y;
                acc[6] += wa[j] * p1.z;
                acc[7] += wa[j] * p1.w;
            }
        }
    }

    // ---------- reduce across the 16 cs lanes (low 4 bits of lane id) ----------
#pragma unroll
    for (int b = 0; b < BATCH; ++b) {
        float v = acc[b];
        v += __shfl_xor(v, 1);
        v += __shfl_xor(v, 2);
        v += __shfl_xor(v, 4);
        v += __shfl_xor(v, 8);
        acc[b] = v;
    }

    if (cs == 0) {
#pragma unroll
        for (int b = 0; b < BATCH; ++b)
            out[(size_t)b * (KN * P_TOTAL) + (size_t)k * P_TOTAL + p] = acc[b];
    }
}

extern "C" void kernel_launch(void* const* d_in, const int* in_sizes, int n_in,
                              void* d_out, int out_size, void* d_ws, size_t ws_size,
                              hipStream_t stream) {
    const float* x    = (const float*)d_in[0];   // [8,16,128,128] f32
    const float* wts  = (const float*)d_in[1];   // [16384,16,144] f32
    const int*   hidx = (const int*)d_in[2];     // [16384,144] int32
    float* out = (float*)d_out;                  // [8,16,16384] f32

    abc2d_kernel<<<P_TOTAL, 256, 0, stream>>>(x, wts, hidx, out);
}

// Round 2
// 242.301 us; speedup vs baseline: 1.5234x; 1.5234x over previous
//
#include <hip/hip_runtime.h>

// Problem constants (from reference)
#define P_TOTAL 16384      // H*W pixels
#define KN      16         // kernels per pixel
#define CK      144        // in_channel * kernel_size
#define BATCH   8
#define IMG     262144     // C*H*W
#define PSTRIDE 12         // padded LDS row stride in floats (48B: float4-aligned)

// ---------------- transpose: x[b][id] -> xt[id][b] ----------------
// Makes each hash gather a single 32B contiguous chunk (one 64B line)
// instead of 8 loads at 1MB stride (8 lines).
__global__ __launch_bounds__(256) void transpose_x(
    const float* __restrict__ x, float* __restrict__ xt)
{
    const int i = blockIdx.x * 256 + threadIdx.x;   // id in [0, IMG)
    float v[BATCH];
#pragma unroll
    for (int b = 0; b < BATCH; ++b) v[b] = x[(size_t)b * IMG + i];  // coalesced per b
    float4* dst = reinterpret_cast<float4*>(xt + (size_t)i * BATCH);
    dst[0] = make_float4(v[0], v[1], v[2], v[3]);   // coalesced 32B/lane store
    dst[1] = make_float4(v[4], v[5], v[6], v[7]);
}

// ---------------- main kernel ----------------
template <bool USE_XT>
__global__ __launch_bounds__(256) void abc2d_kernel(
    const float* __restrict__ xsrc,   // USE_XT ? xt [IMG][8] : x [8][IMG]
    const float* __restrict__ w,      // [P, KN, CK]
    const int*   __restrict__ hidx,   // [P, CK]
    float* __restrict__ out)          // [B, KN, P]
{
    __shared__ float patch[CK * PSTRIDE];   // patch[c][b]

    // XCD swizzle: consecutive p on the same XCD -> output lines merge in L2
    const int bid = blockIdx.x;
    const int p   = (bid & 7) * (P_TOTAL / 8) + (bid >> 3);
    const int t   = threadIdx.x;

    // ---------- gather phase ----------
    const int* hp = hidx + p * CK;
    if (USE_XT) {
        // 288 float4 loads: j -> (c = j>>1, half = j&1)
        for (int j = t; j < CK * 2; j += 256) {
            const int c    = j >> 1;
            const int half = j & 1;
            const int id   = hp[c];
            const float4 v = reinterpret_cast<const float4*>(xsrc)[(size_t)id * 2 + half];
            *reinterpret_cast<float4*>(&patch[c * PSTRIDE + half * 4]) = v;
        }
    } else {
        for (int j = t; j < CK * BATCH; j += 256) {
            const int c = j >> 3;
            const int b = j & 7;
            patch[c * PSTRIDE + b] = xsrc[(size_t)hp[c] + (size_t)b * IMG];
        }
    }
    __syncthreads();

    // ---------- compute phase ----------
    const int k  = t >> 4;
    const int cs = t & 15;
    const float* wp = w + (size_t)p * (KN * CK) + (size_t)k * CK;

    float acc[BATCH];
#pragma unroll
    for (int b = 0; b < BATCH; ++b) acc[b] = 0.f;

#pragma unroll
    for (int i = 0; i < 3; ++i) {
        const int c0 = i * 64 + cs * 4;
        if (c0 < CK) {
            const float4 wv = *reinterpret_cast<const float4*>(wp + c0);
            const float wa[4] = {wv.x, wv.y, wv.z, wv.w};
#pragma unroll
            for (int j = 0; j < 4; ++j) {
                const float* pr = &patch[(c0 + j) * PSTRIDE];
                const float4 p0 = *reinterpret_cast<const float4*>(pr);
                const float4 p1 = *reinterpret_cast<const float4*>(pr + 4);
                acc[0] += wa[j] * p0.x;
                acc[1] += wa[j] * p0.y;
                acc[2] += wa[j] * p0.z;
                acc[3] += wa[j] * p0.w;
                acc[4] += wa[j] * p1.x;
                acc[5] += wa[j] * p1.y;
                acc[6] += wa[j] * p1.z;
                acc[7] += wa[j] * p1.w;
            }
        }
    }

    // ---------- reduce across 16 cs lanes ----------
#pragma unroll
    for (int b = 0; b < BATCH; ++b) {
        float v = acc[b];
        v += __shfl_xor(v, 1);
        v += __shfl_xor(v, 2);
        v += __shfl_xor(v, 4);
        v += __shfl_xor(v, 8);
        acc[b] = v;
    }

    if (cs == 0) {
#pragma unroll
        for (int b = 0; b < BATCH; ++b)
            out[(size_t)b * (KN * P_TOTAL) + (size_t)k * P_TOTAL + p] = acc[b];
    }
}

extern "C" void kernel_launch(void* const* d_in, const int* in_sizes, int n_in,
                              void* d_out, int out_size, void* d_ws, size_t ws_size,
                              hipStream_t stream) {
    const float* x    = (const float*)d_in[0];   // [8,16,128,128] f32
    const float* wts  = (const float*)d_in[1];   // [16384,16,144] f32
    const int*   hidx = (const int*)d_in[2];     // [16384,144] int32
    float* out = (float*)d_out;                  // [8,16,16384] f32

    const size_t xt_bytes = (size_t)IMG * BATCH * sizeof(float);   // 8.39 MB
    if (ws_size >= xt_bytes) {
        float* xt = (float*)d_ws;
        transpose_x<<<IMG / 256, 256, 0, stream>>>(x, xt);
        abc2d_kernel<true><<<P_TOTAL, 256, 0, stream>>>(xt, wts, hidx, out);
    } else {
        abc2d_kernel<false><<<P_TOTAL, 256, 0, stream>>>(x, wts, hidx, out);
    }
}

// Round 3
// 240.317 us; speedup vs baseline: 1.5360x; 1.0083x over previous
//
#include <hip/hip_runtime.h>

// Problem constants (from reference)
#define P_TOTAL 16384      // H*W pixels
#define KN      16         // kernels per pixel
#define CK      144        // in_channel * kernel_size
#define BATCH   8
#define IMG     262144     // C*H*W
#define PSTRIDE 12         // LDS row stride in floats (48B, 16B-aligned for b128)

// ---------------- transpose: x[b][id] -> xt[id][b] ----------------
__global__ __launch_bounds__(256) void transpose_x(
    const float* __restrict__ x, float* __restrict__ xt)
{
    const int i = blockIdx.x * 256 + threadIdx.x;   // id in [0, IMG)
    float v[BATCH];
#pragma unroll
    for (int b = 0; b < BATCH; ++b) v[b] = x[(size_t)b * IMG + i];  // coalesced per b
    float4* dst = reinterpret_cast<float4*>(xt + (size_t)i * BATCH);
    dst[0] = make_float4(v[0], v[1], v[2], v[3]);
    dst[1] = make_float4(v[4], v[5], v[6], v[7]);
}

// ---------------- main kernel ----------------
template <bool USE_XT>
__global__ __launch_bounds__(256) void abc2d_kernel(
    const float* __restrict__ xsrc,   // USE_XT ? xt [IMG][8] : x [8][IMG]
    const float* __restrict__ w,      // [P, KN, CK]
    const int*   __restrict__ hidx,   // [P, CK]
    float* __restrict__ out)          // [B, KN, P]
{
    __shared__ float patch[CK * PSTRIDE];   // patch[c][b]

    // XCD swizzle: consecutive p on the same XCD -> output lines merge in L2
    const int bid = blockIdx.x;
    const int p   = (bid & 7) * (P_TOTAL / 8) + (bid >> 3);
    const int t   = threadIdx.x;

    // ---------- gather phase ----------
    const int* hp = hidx + p * CK;
    if (USE_XT) {
        // 288 float4 loads: j -> (c = j>>1, half = j&1); one 64B line per idx
        for (int j = t; j < CK * 2; j += 256) {
            const int c    = j >> 1;
            const int half = j & 1;
            const int id   = hp[c];
            const float4 v = reinterpret_cast<const float4*>(xsrc)[(size_t)id * 2 + half];
            *reinterpret_cast<float4*>(&patch[c * PSTRIDE + half * 4]) = v;
        }
    } else {
        for (int j = t; j < CK * BATCH; j += 256) {
            const int c = j >> 3;
            const int b = j & 7;
            patch[c * PSTRIDE + b] = xsrc[(size_t)hp[c] + (size_t)b * IMG];
        }
    }
    __syncthreads();

    // ---------- compute phase ----------
    // thread t: k = t>>4, cs = t&15; c = cs + 16*i (stride-16 mapping).
    // LDS bank math: addr step per cs = 12 words, gcd(12,32)=4 -> 16 addrs
    // over 8 banks = 2-way aliasing = free (vs 8-way with the old 4*cs map).
    const int k  = t >> 4;
    const int cs = t & 15;
    const float* wp = w + (size_t)p * (KN * CK) + (size_t)k * CK;

    float acc[BATCH];
#pragma unroll
    for (int b = 0; b < BATCH; ++b) acc[b] = 0.f;

#pragma unroll
    for (int i = 0; i < 9; ++i) {
        const int c = cs + 16 * i;
        const float wv = wp[c];              // coalesced: 16 lanes = 64B run
        const float* pr = &patch[c * PSTRIDE];
        const float4 p0 = *reinterpret_cast<const float4*>(pr);
        const float4 p1 = *reinterpret_cast<const float4*>(pr + 4);
        acc[0] += wv * p0.x;
        acc[1] += wv * p0.y;
        acc[2] += wv * p0.z;
        acc[3] += wv * p0.w;
        acc[4] += wv * p1.x;
        acc[5] += wv * p1.y;
        acc[6] += wv * p1.z;
        acc[7] += wv * p1.w;
    }

    // ---------- reduce across 16 cs lanes ----------
#pragma unroll
    for (int b = 0; b < BATCH; ++b) {
        float v = acc[b];
        v += __shfl_xor(v, 1);
        v += __shfl_xor(v, 2);
        v += __shfl_xor(v, 4);
        v += __shfl_xor(v, 8);
        acc[b] = v;
    }

    if (cs == 0) {
#pragma unroll
        for (int b = 0; b < BATCH; ++b)
            out[(size_t)b * (KN * P_TOTAL) + (size_t)k * P_TOTAL + p] = acc[b];
    }
}

extern "C" void kernel_launch(void* const* d_in, const int* in_sizes, int n_in,
                              void* d_out, int out_size, void* d_ws, size_t ws_size,
                              hipStream_t stream) {
    const float* x    = (const float*)d_in[0];   // [8,16,128,128] f32
    const float* wts  = (const float*)d_in[1];   // [16384,16,144] f32
    const int*   hidx = (const int*)d_in[2];     // [16384,144] int32
    float* out = (float*)d_out;                  // [8,16,16384] f32

    const size_t xt_bytes = (size_t)IMG * BATCH * sizeof(float);   // 8.39 MB
    if (ws_size >= xt_bytes) {
        float* xt = (float*)d_ws;
        transpose_x<<<IMG / 256, 256, 0, stream>>>(x, xt);
        abc2d_kernel<true><<<P_TOTAL, 256, 0, stream>>>(xt, wts, hidx, out);
    } else {
        abc2d_kernel<false><<<P_TOTAL, 256, 0, stream>>>(x, wts, hidx, out);
    }
}

// Round 4
// 239.262 us; speedup vs baseline: 1.5428x; 1.0044x over previous
//
#include <hip/hip_runtime.h>
#include <hip/hip_bf16.h>

// Problem constants (from reference)
#define P_TOTAL 16384      // H*W pixels
#define KN      16         // kernels per pixel
#define CK      144        // in_channel * kernel_size
#define BATCH   8
#define IMG     262144     // C*H*W
#define PSTRIDE 12         // LDS row stride in floats (48B, 16B-aligned for b128)

// ---------------- transpose+quantize: x[b][id] (f32) -> xt[id][b] (bf16) ----------------
// 4.19 MB result ~fits a 4 MB per-XCD L2 -> hash gather becomes mostly L2 hits.
// One gather index = one 16B contiguous chunk (single dwordx4, single line).
__global__ __launch_bounds__(256) void transpose_x_bf16(
    const float* __restrict__ x, float4* __restrict__ xt)
{
    const int i = blockIdx.x * 256 + threadIdx.x;   // id in [0, IMG)
    union { __hip_bfloat16 h[8]; float4 f4; } u;
#pragma unroll
    for (int b = 0; b < BATCH; ++b)
        u.h[b] = __float2bfloat16(x[(size_t)b * IMG + i]);  // coalesced per b
    xt[i] = u.f4;                                            // 16B/lane coalesced store
}

// ---------------- main kernel ----------------
template <bool USE_XT>
__global__ __launch_bounds__(256) void abc2d_kernel(
    const void*  __restrict__ xsrc,   // USE_XT ? xt bf16 [IMG][8] : x f32 [8][IMG]
    const float* __restrict__ w,      // [P, KN, CK]
    const int*   __restrict__ hidx,   // [P, CK]
    float* __restrict__ out)          // [B, KN, P]
{
    __shared__ float patch[CK * PSTRIDE];   // patch[c][b], f32

    // XCD swizzle: consecutive p on the same XCD -> output lines merge in L2
    const int bid = blockIdx.x;
    const int p   = (bid & 7) * (P_TOTAL / 8) + (bid >> 3);
    const int t   = threadIdx.x;
    const int k   = t >> 4;
    const int cs  = t & 15;

    // ---- weight prefetch: issue this global stream BEFORE the gather so the
    // two latencies overlap inside the block (phase-1 = max, not sum) ----
    const float* wp = w + (size_t)p * (KN * CK) + (size_t)k * CK;
    float wreg[9];
#pragma unroll
    for (int i = 0; i < 9; ++i) wreg[i] = wp[cs + 16 * i];   // 16-lane 64B runs

    // ---------- gather phase ----------
    const int* hp = hidx + p * CK;
    if (USE_XT) {
        // one index per thread: 16B bf16x8 load -> f32 LDS row
        if (t < CK) {
            const int id = hp[t];
            union { __hip_bfloat16 h[8]; float4 f4; } u;
            u.f4 = reinterpret_cast<const float4*>(xsrc)[id];
            float* pr = &patch[t * PSTRIDE];
            *reinterpret_cast<float4*>(pr) = make_float4(
                __bfloat162float(u.h[0]), __bfloat162float(u.h[1]),
                __bfloat162float(u.h[2]), __bfloat162float(u.h[3]));
            *reinterpret_cast<float4*>(pr + 4) = make_float4(
                __bfloat162float(u.h[4]), __bfloat162float(u.h[5]),
                __bfloat162float(u.h[6]), __bfloat162float(u.h[7]));
        }
    } else {
        const float* xf = reinterpret_cast<const float*>(xsrc);
        for (int j = t; j < CK * BATCH; j += 256) {
            const int c = j >> 3;
            const int b = j & 7;
            patch[c * PSTRIDE + b] = xf[(size_t)hp[c] + (size_t)b * IMG];
        }
    }
    __syncthreads();

    // ---------- compute phase ----------
    // c = cs + 16*i: LDS word-step 12/lane, gcd(12,32)=4 -> 2-way alias = free
    float acc[BATCH];
#pragma unroll
    for (int b = 0; b < BATCH; ++b) acc[b] = 0.f;

#pragma unroll
    for (int i = 0; i < 9; ++i) {
        const int c = cs + 16 * i;
        const float wv = wreg[i];
        const float* pr = &patch[c * PSTRIDE];
        const float4 p0 = *reinterpret_cast<const float4*>(pr);
        const float4 p1 = *reinterpret_cast<const float4*>(pr + 4);
        acc[0] += wv * p0.x;
        acc[1] += wv * p0.y;
        acc[2] += wv * p0.z;
        acc[3] += wv * p0.w;
        acc[4] += wv * p1.x;
        acc[5] += wv * p1.y;
        acc[6] += wv * p1.z;
        acc[7] += wv * p1.w;
    }

    // ---------- reduce across 16 cs lanes ----------
#pragma unroll
    for (int b = 0; b < BATCH; ++b) {
        float v = acc[b];
        v += __shfl_xor(v, 1);
        v += __shfl_xor(v, 2);
        v += __shfl_xor(v, 4);
        v += __shfl_xor(v, 8);
        acc[b] = v;
    }

    if (cs == 0) {
#pragma unroll
        for (int b = 0; b < BATCH; ++b)
            out[(size_t)b * (KN * P_TOTAL) + (size_t)k * P_TOTAL + p] = acc[b];
    }
}

extern "C" void kernel_launch(void* const* d_in, const int* in_sizes, int n_in,
                              void* d_out, int out_size, void* d_ws, size_t ws_size,
                              hipStream_t stream) {
    const float* x    = (const float*)d_in[0];   // [8,16,128,128] f32
    const float* wts  = (const float*)d_in[1];   // [16384,16,144] f32
    const int*   hidx = (const int*)d_in[2];     // [16384,144] int32
    float* out = (float*)d_out;                  // [8,16,16384] f32

    const size_t xt_bytes = (size_t)IMG * BATCH * sizeof(__hip_bfloat16);  // 4.19 MB
    if (ws_size >= xt_bytes) {
        float4* xt = (float4*)d_ws;
        transpose_x_bf16<<<IMG / 256, 256, 0, stream>>>(x, xt);
        abc2d_kernel<true><<<P_TOTAL, 256, 0, stream>>>((const void*)xt, wts, hidx, out);
    } else {
        abc2d_kernel<false><<<P_TOTAL, 256, 0, stream>>>((const void*)x, wts, hidx, out);
    }
}